// Round 12
// baseline (197.128 us; speedup 1.0000x reference)
//
#include <hip/hip_runtime.h>
#include <hip/hip_fp16.h>

#define EPSV 1e-5f
#define NB  256      // buckets for CSR binning (npb ~391, 9-bit local col)
#define CAP 8192     // bucket capacity (mean ~6250 at E=1.6M, +24 sigma)
#define BIN_ITER 4   // edges per thread in k_bin (static register staging)

typedef short short8 __attribute__((ext_vector_type(8)));
typedef _Float16 half8 __attribute__((ext_vector_type(8)));
typedef float f32x4 __attribute__((ext_vector_type(4)));

__device__ inline unsigned h2u(__half2 h) { union { __half2 h; unsigned u; } c; c.h = h; return c.u; }
__device__ inline __half2 u2h(unsigned u) { union { unsigned u; __half2 h; } c; c.u = u; return c.h; }

// ---------------- W fragment prep + bcnt zeroing (one kernel) ----------------
// f16 split: w = wh + wl, wl = f16(w - wh) -> residual ~2^-22.
// frag (ks, nt, lane): elem e -> W[ks*32 + (lane>>4)*8 + e][nt*16 + (lane&15)]
// layout: out[tid*16] = 8 hi halves, then 8 lo halves

template<int K, int F, int NT>
__device__ inline void wprep_one(const float* __restrict__ W,
                                 unsigned short* __restrict__ out, int tid) {
    const int lane = tid & 63;
    const int nt = (tid >> 6) % NT;
    const int ks = tid / (64 * NT);
    const int col = nt * 16 + (lane & 15);
    const int k0 = ks * 32 + (lane >> 4) * 8;
    half8 h8, l8;
#pragma unroll
    for (int e = 0; e < 8; ++e) {
        const float w = (col < F) ? W[(size_t)(k0 + e) * F + col] : 0.f;
        const _Float16 h = (_Float16)w;
        h8[e] = h;
        l8[e] = (_Float16)(w - (float)h);
    }
    half8* dst = (half8*)(out + (size_t)tid * 16);
    dst[0] = h8;
    dst[1] = l8;
}

__global__ __launch_bounds__(256) void k_prep(const float* __restrict__ W1,
                                              const float* __restrict__ W2,
                                              const float* __restrict__ W3,
                                              unsigned short* __restrict__ wf1,
                                              unsigned short* __restrict__ wf2,
                                              unsigned short* __restrict__ wf3,
                                              int* __restrict__ bcnt) {
    const int bid = blockIdx.x;
    if (bid == 8) {  // zero bucket counters
        if (threadIdx.x < NB) bcnt[threadIdx.x] = 0;
        return;
    }
    const int tid = bid * 256 + threadIdx.x;
    if (tid < 1024) wprep_one<128, 64, 4>(W1, wf1, tid);
    else if (tid < 1536) wprep_one<64, 64, 4>(W2, wf2, tid - 1024);
    else if (tid < 1920) wprep_one<64, 40, 3>(W3, wf3, tid - 1536);
}

// ---------------- phase A: block-aggregated bin by target range ----------------
// entry = (local_col << 17) | row   (requires n <= 131072, npb <= 512)

__global__ __launch_bounds__(1024) void k_bin(const int* __restrict__ row,
                                              const int* __restrict__ col,
                                              int* __restrict__ bcnt,
                                              unsigned* __restrict__ bkt,
                                              int E, int npb) {
    __shared__ int hist[NB];
    __shared__ int fill[NB];
    const int tid = threadIdx.x;
    const int e0 = blockIdx.x * (1024 * BIN_ITER);
    if (tid < NB) hist[tid] = 0;
    __syncthreads();
    unsigned ent[BIN_ITER];
    int bb[BIN_ITER];
#pragma unroll
    for (int j = 0; j < BIN_ITER; ++j) {
        const int i = e0 + j * 1024 + tid;
        bb[j] = -1;
        ent[j] = 0;
        if (i < E) {
            const int c = col[i], r = row[i];
            const int b = c / npb;
            bb[j] = b;
            ent[j] = ((unsigned)(c - b * npb) << 17) | (unsigned)r;
            atomicAdd(&hist[b], 1);
        }
    }
    __syncthreads();
    if (tid < NB)
        fill[tid] = hist[tid] ? atomicAdd(&bcnt[tid], hist[tid]) : 0;
    __syncthreads();
#pragma unroll
    for (int j = 0; j < BIN_ITER; ++j) {
        if (bb[j] >= 0) {
            const int pos = atomicAdd(&fill[bb[j]], 1);
            if (pos < CAP)
                bkt[(size_t)bb[j] * CAP + pos] = ent[j];
        }
    }
}

// ---------------- bucket-base scan (single block, NB threads) ----------------

__global__ __launch_bounds__(NB) void k_bscan(const int* __restrict__ bcnt,
                                              int* __restrict__ bbase,
                                              int* __restrict__ rowptr, int E, int n) {
    __shared__ int s[NB];
    const int t = threadIdx.x;
    const int v = min(bcnt[t], CAP);
    s[t] = v;
    __syncthreads();
    for (int off = 1; off < NB; off <<= 1) {
        int u = (t >= off) ? s[t - off] : 0;
        __syncthreads();
        s[t] += u;
        __syncthreads();
    }
    bbase[t] = s[t] - v;  // exclusive
    if (t == 0) rowptr[n] = E;
}

// ---------------- phase B: per-bucket place + rowptr + dinv ----------------

__global__ __launch_bounds__(256) void k_place(const int* __restrict__ bcnt,
                                               const int* __restrict__ bbase,
                                               const unsigned* __restrict__ bkt,
                                               int* __restrict__ rowptr,
                                               float* __restrict__ dinv,
                                               int* __restrict__ srcidx,
                                               int n, int npb) {
    __shared__ int hist[512];      // npb <= 512
    __shared__ int pfx[512];
    __shared__ unsigned ent[CAP];
    const int b = blockIdx.x;
    const int tid = threadIdx.x;
    const int c0 = b * npb;
    const int nn = min(npb, n - c0);
    if (nn <= 0) return;
    const int bc = min(bcnt[b], CAP);
    const int base = bbase[b];
    for (int j = tid; j < nn; j += 256) hist[j] = 0;
    __syncthreads();
    for (int i = tid; i < bc; i += 256) {
        const unsigned e = bkt[(size_t)b * CAP + i];
        ent[i] = e;
        atomicAdd(&hist[e >> 17], 1);
    }
    __syncthreads();
    if (tid == 0) {
        int run = base;
        for (int j = 0; j < nn; ++j) { pfx[j] = run; run += hist[j]; }
    }
    __syncthreads();
    for (int j = tid; j < nn; j += 256) {
        rowptr[c0 + j] = pfx[j];
        dinv[c0 + j] = rsqrtf((float)(hist[j] + 1));  // +1 self loop
    }
    __syncthreads();
    for (int i = tid; i < bc; i += 256) {
        const unsigned e = ent[i];
        const int pos = atomicAdd(&pfx[e >> 17], 1);  // pfx reused as fill cursor
        srcidx[pos] = (int)(e & 0x1FFFFu);
    }
}

// ---------------- MFMA GEMM, f32 input (layer 1): split-f16 3-MFMA ----------------
// Y packed fp16 pairs (stride 32 half2), scaled by dinv[row]; rows >= n zeroed

template<int K, int NT>
__global__ __launch_bounds__(256) void gemm_f32in(const float* __restrict__ X,
                                                  const unsigned short* __restrict__ wfrag,
                                                  const float* __restrict__ dinv,
                                                  __half2* __restrict__ Y, int n) {
    const int lane = threadIdx.x & 63;
    const int wv = threadIdx.x >> 6;
    const int row0 = blockIdx.x * 64 + wv * 16;
    const int arow = row0 + (lane & 15);
    const bool aval = arow < n;

    f32x4 acc[NT];
#pragma unroll
    for (int t = 0; t < NT; ++t) acc[t] = (f32x4){0.f, 0.f, 0.f, 0.f};

#pragma unroll
    for (int ks = 0; ks < K / 32; ++ks) {
        float av[8];
        if (aval) {
            const float* ap = X + (size_t)arow * K + ks * 32 + (lane >> 4) * 8;
            const float4 p0 = *reinterpret_cast<const float4*>(ap);
            const float4 p1 = *reinterpret_cast<const float4*>(ap + 4);
            av[0] = p0.x; av[1] = p0.y; av[2] = p0.z; av[3] = p0.w;
            av[4] = p1.x; av[5] = p1.y; av[6] = p1.z; av[7] = p1.w;
        } else {
#pragma unroll
            for (int e = 0; e < 8; ++e) av[e] = 0.f;
        }
        half8 ah, al;
#pragma unroll
        for (int e = 0; e < 8; ++e) {
            const _Float16 h = (_Float16)av[e];
            ah[e] = h;
            al[e] = (_Float16)(av[e] - (float)h);
        }
#pragma unroll
        for (int t = 0; t < NT; ++t) {
            const half8* bp = (const half8*)(wfrag + (((size_t)ks * NT + t) * 64 + lane) * 16);
            const half8 bh = bp[0];
            const half8 bl = bp[1];
            acc[t] = __builtin_amdgcn_mfma_f32_16x16x32_f16(ah, bh, acc[t], 0, 0, 0);
            acc[t] = __builtin_amdgcn_mfma_f32_16x16x32_f16(al, bh, acc[t], 0, 0, 0);
            acc[t] = __builtin_amdgcn_mfma_f32_16x16x32_f16(ah, bl, acc[t], 0, 0, 0);
        }
    }

    const int col = lane & 15;
    const int rg = lane >> 4;
#pragma unroll
    for (int r = 0; r < 4; ++r) {
        const int orow = row0 + rg * 4 + r;          // < npad by grid construction
        const float di = (orow < n) ? dinv[orow] : 0.f;
#pragma unroll
        for (int t = 0; t < NT; ++t) {
            const float val = acc[t][r] * di;
            const float oth = __shfl_xor(val, 1);
            if (!(lane & 1))
                Y[(size_t)orow * (NT * 8) + t * 8 + (col >> 1)] = __floats2half2_rn(val, oth);
        }
    }
}

// ---------------- MFMA GEMM, fp16 input (layers 2,3): exact-A 2-MFMA ----------------
// MODE 0: Y packed fp16 * dinv (rows >= n zeroed) | MODE 1: Y f32 (stride 40) + bias

template<int K, int NT, int MODE>
__global__ __launch_bounds__(256) void gemm_f16in(const unsigned short* __restrict__ X,
                                                  const unsigned short* __restrict__ wfrag,
                                                  const float* __restrict__ dinv,
                                                  const float* __restrict__ bias,
                                                  void* __restrict__ Yv, int n) {
    const int lane = threadIdx.x & 63;
    const int wv = threadIdx.x >> 6;
    const int row0 = blockIdx.x * 64 + wv * 16;
    const int arow = row0 + (lane & 15);
    const bool aval = arow < n;

    f32x4 acc[NT];
#pragma unroll
    for (int t = 0; t < NT; ++t) acc[t] = (f32x4){0.f, 0.f, 0.f, 0.f};

#pragma unroll
    for (int ks = 0; ks < K / 32; ++ks) {
        half8 ah = {0, 0, 0, 0, 0, 0, 0, 0};
        if (aval)
            ah = *(const half8*)(X + (size_t)arow * K + ks * 32 + (lane >> 4) * 8);
#pragma unroll
        for (int t = 0; t < NT; ++t) {
            const half8* bp = (const half8*)(wfrag + (((size_t)ks * NT + t) * 64 + lane) * 16);
            const half8 bh = bp[0];
            const half8 bl = bp[1];
            acc[t] = __builtin_amdgcn_mfma_f32_16x16x32_f16(ah, bh, acc[t], 0, 0, 0);
            acc[t] = __builtin_amdgcn_mfma_f32_16x16x32_f16(ah, bl, acc[t], 0, 0, 0);
        }
    }

    const int col = lane & 15;
    const int rg = lane >> 4;
#pragma unroll
    for (int r = 0; r < 4; ++r) {
        const int orow = row0 + rg * 4 + r;
        if (MODE == 0) {
            const float di = (orow < n) ? dinv[orow] : 0.f;
            __half2* Y = (__half2*)Yv;
#pragma unroll
            for (int t = 0; t < NT; ++t) {
                const float val = acc[t][r] * di;
                const float oth = __shfl_xor(val, 1);
                if (!(lane & 1))
                    Y[(size_t)orow * (NT * 8) + t * 8 + (col >> 1)] = __floats2half2_rn(val, oth);
            }
        } else {
            float* Y = (float*)Yv;
#pragma unroll
            for (int t = 0; t < NT; ++t) {
                const int oc = t * 16 + col;
                if (orow < n && oc < 40)
                    Y[(size_t)orow * 40 + oc] = acc[t][r] + bias[oc];
            }
        }
    }
}

// ---------------- fp16 gather-reduce: LDS-staged offsets + v_pk_add_f16 ----------------
// in: packed fp16 pairs, row stride 32 half2; row n (pad) must be all-zero.
// Wave per node. Lane p=l&31 owns feature pair (2p,2p+1); halves do even/odd edges.
// Inner: groups of 8 independent {ds_read(imm) -> v_add -> global_load -> pk_add}.
// MODE 0: out = relu(bn(acc*dinv)) ; MODE 1: same * dinv ; MODE 2: acc*dinv

template<int MODE>
__global__ __launch_bounds__(256) void k_gather(const __half2* __restrict__ in,
                                                const int* __restrict__ rowptr,
                                                const int* __restrict__ srcidx,
                                                const float* __restrict__ dinv,
                                                const float* __restrict__ b,
                                                const float* __restrict__ g,
                                                const float* __restrict__ be,
                                                const float* __restrict__ m,
                                                const float* __restrict__ v,
                                                __half2* __restrict__ out, int n) {
    __shared__ unsigned offs[4][64];
    const int lane = threadIdx.x & 63;
    const int wslot = threadIdx.x >> 6;
    const int half = lane >> 5;
    const int p = lane & 31;
    const int node = blockIdx.x * 4 + wslot;

    if (node >= n) {  // pad node: keep pad rows of `out` zeroed
        if (!half) out[(size_t)node * 32 + p] = u2h(0u);
        return;
    }

    const int s = rowptr[node], e = rowptr[node + 1];
    const unsigned pconst = (unsigned)p * 4u;
    const char* inb = (const char*)in;
    __half2 acc0 = u2h(0u), acc1 = u2h(0u), acc2 = u2h(0u), acc3 = u2h(0u);

    for (int base = s; base < e; base += 64) {
        const int c = min(64, e - base);
        unsigned idx = (unsigned)n;  // pad row (zeros) for out-of-range slots
        if (base + lane < e) idx = (unsigned)srcidx[base + lane];
        offs[wslot][lane] = idx * 128u;  // row byte offset
        // groups of 8 steps; each step covers 2 edges (one per half)
        for (int k8 = 0; k8 < 32; k8 += 8) {
            if (2 * k8 >= c) break;
            unsigned o[8], u[8];
#pragma unroll
            for (int j = 0; j < 8; ++j) o[j] = offs[wslot][2 * (k8 + j) + half];
#pragma unroll
            for (int j = 0; j < 8; ++j)
                u[j] = *(const unsigned*)(inb + (size_t)(o[j] + pconst));
            acc0 = __hadd2(acc0, u2h(u[0])); acc1 = __hadd2(acc1, u2h(u[1]));
            acc2 = __hadd2(acc2, u2h(u[2])); acc3 = __hadd2(acc3, u2h(u[3]));
            acc0 = __hadd2(acc0, u2h(u[4])); acc1 = __hadd2(acc1, u2h(u[5]));
            acc2 = __hadd2(acc2, u2h(u[6])); acc3 = __hadd2(acc3, u2h(u[7]));
        }
    }
    __half2 acc = __hadd2(__hadd2(acc0, acc1), __hadd2(acc2, acc3));
    acc = __hadd2(acc, u2h(__shfl_xor(h2u(acc), 32)));
    // convert to f32, add self loop in f32
    float2 af = __half22float2(acc);
    const float2 sf = __half22float2(in[(size_t)node * 32 + p]);
    float ax = af.x + sf.x, ay = af.y + sf.y;

    const float di = dinv[node];
    float ox, oy;
    if (MODE == 2) {
        ox = ax * di; oy = ay * di;
    } else {
        const float2 bb = ((const float2*)b)[p];
        const float2 gg = ((const float2*)g)[p];
        const float2 bee = ((const float2*)be)[p];
        const float2 mm = ((const float2*)m)[p];
        const float2 vv = ((const float2*)v)[p];
        const float sx = gg.x * rsqrtf(vv.x + EPSV);
        const float sy = gg.y * rsqrtf(vv.y + EPSV);
        ox = fmaxf((ax * di + bb.x - mm.x) * sx + bee.x, 0.f);
        oy = fmaxf((ay * di + bb.y - mm.y) * sy + bee.y, 0.f);
        if (MODE == 1) { ox *= di; oy *= di; }
    }
    if (!half) out[(size_t)node * 32 + p] = __floats2half2_rn(ox, oy);
}

// ---------------- launch ----------------

extern "C" void kernel_launch(void* const* d_in, const int* in_sizes, int n_in,
                              void* d_out, int out_size, void* d_ws, size_t ws_size,
                              hipStream_t stream) {
    const float* x   = (const float*)d_in[0];
    const int*   ei  = (const int*)d_in[1];
    const float* W1  = (const float*)d_in[2];
    const float* b1  = (const float*)d_in[3];
    const float* g1  = (const float*)d_in[4];
    const float* be1 = (const float*)d_in[5];
    const float* m1  = (const float*)d_in[6];
    const float* v1  = (const float*)d_in[7];
    const float* W2  = (const float*)d_in[8];
    const float* b2  = (const float*)d_in[9];
    const float* g2  = (const float*)d_in[10];
    const float* be2 = (const float*)d_in[11];
    const float* m2  = (const float*)d_in[12];
    const float* v2  = (const float*)d_in[13];
    const float* W3  = (const float*)d_in[14];
    const float* b3  = (const float*)d_in[15];

    const int n = in_sizes[0] / 128;
    const int E = in_sizes[1] / 2;
    const int* row  = ei;       // source nodes
    const int* colv = ei + E;   // target nodes
    const int npb = (n + NB - 1) / NB;    // nodes per bucket (391 for n=100k; <=512)
    const int gblk = (n >> 6) + 1;        // guarantees >=1 pad row (row n zeroed)
    const int npad = gblk * 64;

    char* base = (char*)d_ws;
    size_t off = 0;
    auto alloc = [&](size_t bytes) -> char* {
        char* p = base + off;
        off += (bytes + 255) & ~(size_t)255;
        return p;
    };
    int*      bcnt   = (int*)     alloc((size_t)NB * 4);
    int*      bbase  = (int*)     alloc((size_t)NB * 4);
    unsigned* bkt    = (unsigned*)alloc((size_t)NB * CAP * 4);
    int*      rowptr = (int*)     alloc((size_t)(n + 1) * 4);
    int*      srcidx = (int*)     alloc((size_t)E * 4);
    float*    dinv   = (float*)   alloc((size_t)n * 4);
    __half2*  hls1u  = (__half2*) alloc((size_t)npad * 32 * 4);   // (x@W1)*dinv   fp16
    __half2*  h1u    = (__half2*) alloc((size_t)npad * 32 * 4);   // h1            fp16
    __half2*  hls2u  = (__half2*) alloc((size_t)npad * 32 * 4);   // (h1@W2)*dinv  fp16
    __half2*  h2lsu  = (__half2*) alloc((size_t)npad * 32 * 4);   // h2*dinv       fp16
    __half2*  agg3u  = (__half2*) alloc((size_t)npad * 32 * 4);   // A_norm@h2     fp16
    unsigned short* wf1 = (unsigned short*)alloc((size_t)(128/32) * 4 * 64 * 32);
    unsigned short* wf2 = (unsigned short*)alloc((size_t)(64/32) * 4 * 64 * 32);
    unsigned short* wf3 = (unsigned short*)alloc((size_t)(64/32) * 3 * 64 * 32);
    float*    outp   = (float*)d_out;

    // prep: weight fragments + zero bucket counters (one kernel)
    k_prep<<<9, 256, 0, stream>>>(W1, W2, W3, wf1, wf2, wf3, bcnt);

    // CSR build (binned counting sort; also produces dinv)
    const int binblk = (E + 1024 * BIN_ITER - 1) / (1024 * BIN_ITER);
    k_bin<<<binblk, 1024, 0, stream>>>(row, colv, bcnt, bkt, E, npb);
    k_bscan<<<1, NB, 0, stream>>>(bcnt, bbase, rowptr, E, n);
    k_place<<<NB, 256, 0, stream>>>(bcnt, bbase, bkt, rowptr, dinv, srcidx, n, npb);

    const int ablk = npad / 4;
    // layer 1
    gemm_f32in<128, 4><<<gblk, 256, 0, stream>>>(x, wf1, dinv, hls1u, n);
    k_gather<0><<<ablk, 256, 0, stream>>>(hls1u, rowptr, srcidx, dinv,
                                          b1, g1, be1, m1, v1, h1u, n);
    // layer 2
    gemm_f16in<64, 4, 0><<<gblk, 256, 0, stream>>>((const unsigned short*)h1u, wf2,
                                                   dinv, nullptr, hls2u, n);
    k_gather<1><<<ablk, 256, 0, stream>>>(hls2u, rowptr, srcidx, dinv,
                                          b2, g2, be2, m2, v2, h2lsu, n);
    // layer 3: aggregate h2*dinv first, then transform 64->40
    k_gather<2><<<ablk, 256, 0, stream>>>(h2lsu, rowptr, srcidx, dinv,
                                          nullptr, nullptr, nullptr, nullptr, nullptr,
                                          agg3u, n);
    gemm_f16in<64, 3, 1><<<gblk, 256, 0, stream>>>((const unsigned short*)agg3u, wf3,
                                                   dinv, b3, outp, n);
}

// Round 13
// 174.373 us; speedup vs baseline: 1.1305x; 1.1305x over previous
//
#include <hip/hip_runtime.h>
#include <hip/hip_fp16.h>

#define EPSV 1e-5f
#define NB  1024     // buckets for CSR binning (npb ~98, 7-bit local col fits 15-bit field)
#define CAP 2048     // bucket capacity (mean ~1563 at E=1.6M)
#define BIN_ITER 4   // edges per thread in k_bin (static register staging)

typedef short short8 __attribute__((ext_vector_type(8)));
typedef _Float16 half8 __attribute__((ext_vector_type(8)));
typedef float f32x4 __attribute__((ext_vector_type(4)));

__device__ inline unsigned h2u(__half2 h) { union { __half2 h; unsigned u; } c; c.h = h; return c.u; }
__device__ inline __half2 u2h(unsigned u) { union { unsigned u; __half2 h; } c; c.u = u; return c.h; }

// ---------------- W fragment prep + bcnt zeroing (one kernel) ----------------
// f16 split: w = wh + wl, wl = f16(w - wh) -> residual ~2^-22.
// frag (ks, nt, lane): elem e -> W[ks*32 + (lane>>4)*8 + e][nt*16 + (lane&15)]
// layout: out[tid*16] = 8 hi halves, then 8 lo halves

template<int K, int F, int NT>
__device__ inline void wprep_one(const float* __restrict__ W,
                                 unsigned short* __restrict__ out, int tid) {
    const int lane = tid & 63;
    const int nt = (tid >> 6) % NT;
    const int ks = tid / (64 * NT);
    const int col = nt * 16 + (lane & 15);
    const int k0 = ks * 32 + (lane >> 4) * 8;
    half8 h8, l8;
#pragma unroll
    for (int e = 0; e < 8; ++e) {
        const float w = (col < F) ? W[(size_t)(k0 + e) * F + col] : 0.f;
        const _Float16 h = (_Float16)w;
        h8[e] = h;
        l8[e] = (_Float16)(w - (float)h);
    }
    half8* dst = (half8*)(out + (size_t)tid * 16);
    dst[0] = h8;
    dst[1] = l8;
}

__global__ __launch_bounds__(256) void k_prep(const float* __restrict__ W1,
                                              const float* __restrict__ W2,
                                              const float* __restrict__ W3,
                                              unsigned short* __restrict__ wf1,
                                              unsigned short* __restrict__ wf2,
                                              unsigned short* __restrict__ wf3,
                                              int* __restrict__ bcnt) {
    const int bid = blockIdx.x;
    if (bid == 8) {  // zero bucket counters
        for (int i = threadIdx.x; i < NB; i += 256) bcnt[i] = 0;
        return;
    }
    const int tid = bid * 256 + threadIdx.x;
    if (tid < 1024) wprep_one<128, 64, 4>(W1, wf1, tid);
    else if (tid < 1536) wprep_one<64, 64, 4>(W2, wf2, tid - 1024);
    else if (tid < 1920) wprep_one<64, 40, 3>(W3, wf3, tid - 1536);
}

// ---------------- phase A: block-aggregated bin by target range ----------------
// entry = (local_col << 17) | row   (requires n <= 131072)

__global__ __launch_bounds__(1024) void k_bin(const int* __restrict__ row,
                                              const int* __restrict__ col,
                                              int* __restrict__ bcnt,
                                              unsigned* __restrict__ bkt,
                                              int E, int npb) {
    __shared__ int hist[NB];
    __shared__ int fill[NB];
    const int tid = threadIdx.x;
    const int e0 = blockIdx.x * (1024 * BIN_ITER);
    if (tid < NB) hist[tid] = 0;
    __syncthreads();
    unsigned ent[BIN_ITER];
    int bb[BIN_ITER];
#pragma unroll
    for (int j = 0; j < BIN_ITER; ++j) {
        const int i = e0 + j * 1024 + tid;
        bb[j] = -1;
        ent[j] = 0;
        if (i < E) {
            const int c = col[i], r = row[i];
            const int b = c / npb;
            bb[j] = b;
            ent[j] = ((unsigned)(c - b * npb) << 17) | (unsigned)r;
            atomicAdd(&hist[b], 1);
        }
    }
    __syncthreads();
    if (tid < NB)
        fill[tid] = hist[tid] ? atomicAdd(&bcnt[tid], hist[tid]) : 0;
    __syncthreads();
#pragma unroll
    for (int j = 0; j < BIN_ITER; ++j) {
        if (bb[j] >= 0) {
            const int pos = atomicAdd(&fill[bb[j]], 1);
            if (pos < CAP)
                bkt[(size_t)bb[j] * CAP + pos] = ent[j];
        }
    }
}

// ---------------- bucket-base scan (single block, NB threads) ----------------

__global__ __launch_bounds__(NB) void k_bscan(const int* __restrict__ bcnt,
                                              int* __restrict__ bbase,
                                              int* __restrict__ rowptr, int E, int n) {
    __shared__ int s[NB];
    const int t = threadIdx.x;
    const int v = min(bcnt[t], CAP);
    s[t] = v;
    __syncthreads();
    for (int off = 1; off < NB; off <<= 1) {
        int u = (t >= off) ? s[t - off] : 0;
        __syncthreads();
        s[t] += u;
        __syncthreads();
    }
    bbase[t] = s[t] - v;  // exclusive
    if (t == 0) rowptr[n] = E;
}

// ---------------- phase B: per-bucket place + rowptr + dinv ----------------

__global__ __launch_bounds__(256) void k_place(const int* __restrict__ bcnt,
                                               const int* __restrict__ bbase,
                                               const unsigned* __restrict__ bkt,
                                               int* __restrict__ rowptr,
                                               float* __restrict__ dinv,
                                               int* __restrict__ srcidx,
                                               int n, int npb) {
    __shared__ int hist[128];      // npb <= 128
    __shared__ int pfx[128];
    __shared__ unsigned ent[CAP];
    const int b = blockIdx.x;
    const int tid = threadIdx.x;
    const int c0 = b * npb;
    const int nn = min(npb, n - c0);
    if (nn <= 0) return;
    const int bc = min(bcnt[b], CAP);
    const int base = bbase[b];
    for (int j = tid; j < nn; j += 256) hist[j] = 0;
    __syncthreads();
    for (int i = tid; i < bc; i += 256) {
        const unsigned e = bkt[(size_t)b * CAP + i];
        ent[i] = e;
        atomicAdd(&hist[e >> 17], 1);
    }
    __syncthreads();
    if (tid == 0) {
        int run = base;
        for (int j = 0; j < nn; ++j) { pfx[j] = run; run += hist[j]; }
    }
    __syncthreads();
    for (int j = tid; j < nn; j += 256) {
        rowptr[c0 + j] = pfx[j];
        dinv[c0 + j] = rsqrtf((float)(hist[j] + 1));  // +1 self loop
    }
    __syncthreads();
    for (int i = tid; i < bc; i += 256) {
        const unsigned e = ent[i];
        const int pos = atomicAdd(&pfx[e >> 17], 1);  // pfx reused as fill cursor
        srcidx[pos] = (int)(e & 0x1FFFFu);
    }
}

// ---------------- MFMA GEMM, f32 input (layer 1): split-f16 3-MFMA ----------------
// Y packed fp16 pairs (stride 32 half2), scaled by dinv[row]; rows >= n zeroed

template<int K, int NT>
__global__ __launch_bounds__(256) void gemm_f32in(const float* __restrict__ X,
                                                  const unsigned short* __restrict__ wfrag,
                                                  const float* __restrict__ dinv,
                                                  __half2* __restrict__ Y, int n) {
    const int lane = threadIdx.x & 63;
    const int wv = threadIdx.x >> 6;
    const int row0 = blockIdx.x * 64 + wv * 16;
    const int arow = row0 + (lane & 15);
    const bool aval = arow < n;

    f32x4 acc[NT];
#pragma unroll
    for (int t = 0; t < NT; ++t) acc[t] = (f32x4){0.f, 0.f, 0.f, 0.f};

#pragma unroll
    for (int ks = 0; ks < K / 32; ++ks) {
        float av[8];
        if (aval) {
            const float* ap = X + (size_t)arow * K + ks * 32 + (lane >> 4) * 8;
            const float4 p0 = *reinterpret_cast<const float4*>(ap);
            const float4 p1 = *reinterpret_cast<const float4*>(ap + 4);
            av[0] = p0.x; av[1] = p0.y; av[2] = p0.z; av[3] = p0.w;
            av[4] = p1.x; av[5] = p1.y; av[6] = p1.z; av[7] = p1.w;
        } else {
#pragma unroll
            for (int e = 0; e < 8; ++e) av[e] = 0.f;
        }
        half8 ah, al;
#pragma unroll
        for (int e = 0; e < 8; ++e) {
            const _Float16 h = (_Float16)av[e];
            ah[e] = h;
            al[e] = (_Float16)(av[e] - (float)h);
        }
#pragma unroll
        for (int t = 0; t < NT; ++t) {
            const half8* bp = (const half8*)(wfrag + (((size_t)ks * NT + t) * 64 + lane) * 16);
            const half8 bh = bp[0];
            const half8 bl = bp[1];
            acc[t] = __builtin_amdgcn_mfma_f32_16x16x32_f16(ah, bh, acc[t], 0, 0, 0);
            acc[t] = __builtin_amdgcn_mfma_f32_16x16x32_f16(al, bh, acc[t], 0, 0, 0);
            acc[t] = __builtin_amdgcn_mfma_f32_16x16x32_f16(ah, bl, acc[t], 0, 0, 0);
        }
    }

    const int col = lane & 15;
    const int rg = lane >> 4;
#pragma unroll
    for (int r = 0; r < 4; ++r) {
        const int orow = row0 + rg * 4 + r;          // < npad by grid construction
        const float di = (orow < n) ? dinv[orow] : 0.f;
#pragma unroll
        for (int t = 0; t < NT; ++t) {
            const float val = acc[t][r] * di;
            const float oth = __shfl_xor(val, 1);
            if (!(lane & 1))
                Y[(size_t)orow * (NT * 8) + t * 8 + (col >> 1)] = __floats2half2_rn(val, oth);
        }
    }
}

// ---------------- MFMA GEMM, fp16 input (layers 2,3): exact-A 2-MFMA ----------------
// MODE 0: Y packed fp16 * dinv (rows >= n zeroed) | MODE 1: Y f32 (stride 40) + bias

template<int K, int NT, int MODE>
__global__ __launch_bounds__(256) void gemm_f16in(const unsigned short* __restrict__ X,
                                                  const unsigned short* __restrict__ wfrag,
                                                  const float* __restrict__ dinv,
                                                  const float* __restrict__ bias,
                                                  void* __restrict__ Yv, int n) {
    const int lane = threadIdx.x & 63;
    const int wv = threadIdx.x >> 6;
    const int row0 = blockIdx.x * 64 + wv * 16;
    const int arow = row0 + (lane & 15);
    const bool aval = arow < n;

    f32x4 acc[NT];
#pragma unroll
    for (int t = 0; t < NT; ++t) acc[t] = (f32x4){0.f, 0.f, 0.f, 0.f};

#pragma unroll
    for (int ks = 0; ks < K / 32; ++ks) {
        half8 ah = {0, 0, 0, 0, 0, 0, 0, 0};
        if (aval)
            ah = *(const half8*)(X + (size_t)arow * K + ks * 32 + (lane >> 4) * 8);
#pragma unroll
        for (int t = 0; t < NT; ++t) {
            const half8* bp = (const half8*)(wfrag + (((size_t)ks * NT + t) * 64 + lane) * 16);
            const half8 bh = bp[0];
            const half8 bl = bp[1];
            acc[t] = __builtin_amdgcn_mfma_f32_16x16x32_f16(ah, bh, acc[t], 0, 0, 0);
            acc[t] = __builtin_amdgcn_mfma_f32_16x16x32_f16(ah, bl, acc[t], 0, 0, 0);
        }
    }

    const int col = lane & 15;
    const int rg = lane >> 4;
#pragma unroll
    for (int r = 0; r < 4; ++r) {
        const int orow = row0 + rg * 4 + r;
        if (MODE == 0) {
            const float di = (orow < n) ? dinv[orow] : 0.f;
            __half2* Y = (__half2*)Yv;
#pragma unroll
            for (int t = 0; t < NT; ++t) {
                const float val = acc[t][r] * di;
                const float oth = __shfl_xor(val, 1);
                if (!(lane & 1))
                    Y[(size_t)orow * (NT * 8) + t * 8 + (col >> 1)] = __floats2half2_rn(val, oth);
            }
        } else {
            float* Y = (float*)Yv;
#pragma unroll
            for (int t = 0; t < NT; ++t) {
                const int oc = t * 16 + col;
                if (orow < n && oc < 40)
                    Y[(size_t)orow * 40 + oc] = acc[t][r] + bias[oc];
            }
        }
    }
}

// ---------------- fp16 gather-reduce: persistent waves, LDS-staged offsets ----------------
// in: packed fp16 pairs, row stride 32 half2; row n (pad) must be all-zero.
// Fixed grid; each wave grid-strides over nodes. Lane p=l&31 owns feature pair
// (2p,2p+1); halves do even/odd edges. Inner loop: groups of 8 independent
// {ds_read(imm) -> v_add -> global_load -> v_pk_add_f16}. BN params hoisted.
// MODE 0: out = relu(bn(acc*dinv)) ; MODE 1: same * dinv ; MODE 2: acc*dinv

template<int MODE>
__global__ __launch_bounds__(256) void k_gather(const __half2* __restrict__ in,
                                                const int* __restrict__ rowptr,
                                                const int* __restrict__ srcidx,
                                                const float* __restrict__ dinv,
                                                const float* __restrict__ b,
                                                const float* __restrict__ g,
                                                const float* __restrict__ be,
                                                const float* __restrict__ m,
                                                const float* __restrict__ v,
                                                __half2* __restrict__ out,
                                                int n, int npad) {
    __shared__ unsigned offs[4][64];
    const int lane = threadIdx.x & 63;
    const int wslot = threadIdx.x >> 6;
    const int half = lane >> 5;
    const int p = lane & 31;
    const int wid0 = blockIdx.x * 4 + wslot;
    const int nwaves = gridDim.x * 4;
    const unsigned pconst = (unsigned)p * 4u;
    const char* inb = (const char*)in;

    // hoisted BN params (uniform across nodes)
    float sx = 0.f, sy = 0.f;
    float2 bb = {0.f, 0.f}, mm = {0.f, 0.f}, bee = {0.f, 0.f};
    if (MODE != 2) {
        bb = ((const float2*)b)[p];
        const float2 gg = ((const float2*)g)[p];
        bee = ((const float2*)be)[p];
        mm = ((const float2*)m)[p];
        const float2 vv = ((const float2*)v)[p];
        sx = gg.x * rsqrtf(vv.x + EPSV);
        sy = gg.y * rsqrtf(vv.y + EPSV);
    }

    for (int node = wid0; node < npad; node += nwaves) {
        if (node >= n) {  // pad node: keep pad rows of `out` zeroed
            if (!half) out[(size_t)node * 32 + p] = u2h(0u);
            continue;
        }
        const int s = rowptr[node], e = rowptr[node + 1];
        __half2 acc0 = u2h(0u), acc1 = u2h(0u), acc2 = u2h(0u), acc3 = u2h(0u);

        for (int base = s; base < e; base += 64) {
            const int c = min(64, e - base);
            unsigned idx = (unsigned)n;  // pad row (zeros) for out-of-range slots
            if (base + lane < e) idx = (unsigned)srcidx[base + lane];
            offs[wslot][lane] = idx * 128u;  // row byte offset
            for (int k8 = 0; k8 < 32; k8 += 8) {
                if (2 * k8 >= c) break;
                unsigned o[8], u[8];
#pragma unroll
                for (int j = 0; j < 8; ++j) o[j] = offs[wslot][2 * (k8 + j) + half];
#pragma unroll
                for (int j = 0; j < 8; ++j)
                    u[j] = *(const unsigned*)(inb + (size_t)(o[j] + pconst));
                acc0 = __hadd2(acc0, u2h(u[0])); acc1 = __hadd2(acc1, u2h(u[1]));
                acc2 = __hadd2(acc2, u2h(u[2])); acc3 = __hadd2(acc3, u2h(u[3]));
                acc0 = __hadd2(acc0, u2h(u[4])); acc1 = __hadd2(acc1, u2h(u[5]));
                acc2 = __hadd2(acc2, u2h(u[6])); acc3 = __hadd2(acc3, u2h(u[7]));
            }
        }
        __half2 acc = __hadd2(__hadd2(acc0, acc1), __hadd2(acc2, acc3));
        acc = __hadd2(acc, u2h(__shfl_xor(h2u(acc), 32)));
        // convert to f32, add self loop in f32
        float2 af = __half22float2(acc);
        const float2 sf = __half22float2(in[(size_t)node * 32 + p]);
        const float ax = af.x + sf.x, ay = af.y + sf.y;

        const float di = dinv[node];
        float ox, oy;
        if (MODE == 2) {
            ox = ax * di; oy = ay * di;
        } else {
            ox = fmaxf((ax * di + bb.x - mm.x) * sx + bee.x, 0.f);
            oy = fmaxf((ay * di + bb.y - mm.y) * sy + bee.y, 0.f);
            if (MODE == 1) { ox *= di; oy *= di; }
        }
        if (!half) out[(size_t)node * 32 + p] = __floats2half2_rn(ox, oy);
    }
}

// ---------------- launch ----------------

extern "C" void kernel_launch(void* const* d_in, const int* in_sizes, int n_in,
                              void* d_out, int out_size, void* d_ws, size_t ws_size,
                              hipStream_t stream) {
    const float* x   = (const float*)d_in[0];
    const int*   ei  = (const int*)d_in[1];
    const float* W1  = (const float*)d_in[2];
    const float* b1  = (const float*)d_in[3];
    const float* g1  = (const float*)d_in[4];
    const float* be1 = (const float*)d_in[5];
    const float* m1  = (const float*)d_in[6];
    const float* v1  = (const float*)d_in[7];
    const float* W2  = (const float*)d_in[8];
    const float* b2  = (const float*)d_in[9];
    const float* g2  = (const float*)d_in[10];
    const float* be2 = (const float*)d_in[11];
    const float* m2  = (const float*)d_in[12];
    const float* v2  = (const float*)d_in[13];
    const float* W3  = (const float*)d_in[14];
    const float* b3  = (const float*)d_in[15];

    const int n = in_sizes[0] / 128;
    const int E = in_sizes[1] / 2;
    const int* row  = ei;       // source nodes
    const int* colv = ei + E;   // target nodes
    const int npb = (n + NB - 1) / NB;    // nodes per bucket (98 for n=100k; <=128)
    const int gblk = (n >> 6) + 1;        // guarantees >=1 pad row (row n zeroed)
    const int npad = gblk * 64;

    char* base = (char*)d_ws;
    size_t off = 0;
    auto alloc = [&](size_t bytes) -> char* {
        char* p = base + off;
        off += (bytes + 255) & ~(size_t)255;
        return p;
    };
    int*      bcnt   = (int*)     alloc((size_t)NB * 4);
    int*      bbase  = (int*)     alloc((size_t)NB * 4);
    unsigned* bkt    = (unsigned*)alloc((size_t)NB * CAP * 4);
    int*      rowptr = (int*)     alloc((size_t)(n + 1) * 4);
    int*      srcidx = (int*)     alloc((size_t)E * 4);
    float*    dinv   = (float*)   alloc((size_t)n * 4);
    __half2*  hls1u  = (__half2*) alloc((size_t)npad * 32 * 4);   // (x@W1)*dinv   fp16
    __half2*  h1u    = (__half2*) alloc((size_t)npad * 32 * 4);   // h1            fp16
    __half2*  hls2u  = (__half2*) alloc((size_t)npad * 32 * 4);   // (h1@W2)*dinv  fp16
    __half2*  h2lsu  = (__half2*) alloc((size_t)npad * 32 * 4);   // h2*dinv       fp16
    __half2*  agg3u  = (__half2*) alloc((size_t)npad * 32 * 4);   // A_norm@h2     fp16
    unsigned short* wf1 = (unsigned short*)alloc((size_t)(128/32) * 4 * 64 * 32);
    unsigned short* wf2 = (unsigned short*)alloc((size_t)(64/32) * 4 * 64 * 32);
    unsigned short* wf3 = (unsigned short*)alloc((size_t)(64/32) * 3 * 64 * 32);
    float*    outp   = (float*)d_out;

    // prep: weight fragments + zero bucket counters (one kernel)
    k_prep<<<9, 256, 0, stream>>>(W1, W2, W3, wf1, wf2, wf3, bcnt);

    // CSR build (binned counting sort; also produces dinv)
    const int binblk = (E + 1024 * BIN_ITER - 1) / (1024 * BIN_ITER);
    k_bin<<<binblk, 1024, 0, stream>>>(row, colv, bcnt, bkt, E, npb);
    k_bscan<<<1, NB, 0, stream>>>(bcnt, bbase, rowptr, E, n);
    k_place<<<NB, 256, 0, stream>>>(bcnt, bbase, bkt, rowptr, dinv, srcidx, n, npb);

    const int ablk = 2048;  // persistent gather grid (8192 waves)
    // layer 1
    gemm_f32in<128, 4><<<gblk, 256, 0, stream>>>(x, wf1, dinv, hls1u, n);
    k_gather<0><<<ablk, 256, 0, stream>>>(hls1u, rowptr, srcidx, dinv,
                                          b1, g1, be1, m1, v1, h1u, n, npad);
    // layer 2
    gemm_f16in<64, 4, 0><<<gblk, 256, 0, stream>>>((const unsigned short*)h1u, wf2,
                                                   dinv, nullptr, hls2u, n);
    k_gather<1><<<ablk, 256, 0, stream>>>(hls2u, rowptr, srcidx, dinv,
                                          b2, g2, be2, m2, v2, h2lsu, n, npad);
    // layer 3: aggregate h2*dinv first, then transform 64->40
    k_gather<2><<<ablk, 256, 0, stream>>>(h2lsu, rowptr, srcidx, dinv,
                                          nullptr, nullptr, nullptr, nullptr, nullptr,
                                          agg3u, n, npad);
    gemm_f16in<64, 3, 1><<<gblk, 256, 0, stream>>>((const unsigned short*)agg3u, wf3,
                                                   dinv, b3, outp, n);
}

// Round 14
// 173.877 us; speedup vs baseline: 1.1337x; 1.0028x over previous
//
#include <hip/hip_runtime.h>
#include <hip/hip_fp16.h>

#define EPSV 1e-5f
#define NB  1024     // buckets for CSR binning (npb ~98, 7-bit local col fits 15-bit field)
#define CAP 2048     // bucket capacity (mean ~1563 at E=1.6M)
#define BIN_ITER 4   // edges per thread in k_bin (static register staging)

typedef short short8 __attribute__((ext_vector_type(8)));
typedef _Float16 half8 __attribute__((ext_vector_type(8)));
typedef float f32x4 __attribute__((ext_vector_type(4)));

__device__ inline unsigned h2u(__half2 h) { union { __half2 h; unsigned u; } c; c.h = h; return c.u; }
__device__ inline __half2 u2h(unsigned u) { union { unsigned u; __half2 h; } c; c.u = u; return c.h; }

// ---------------- W fragment prep + bcnt zeroing (one kernel) ----------------
// f16 split: w = wh + wl, wl = f16(w - wh) -> residual ~2^-22.
// frag (ks, nt, lane): elem e -> W[ks*32 + (lane>>4)*8 + e][nt*16 + (lane&15)]
// layout: out[tid*16] = 8 hi halves, then 8 lo halves

template<int K, int F, int NT>
__device__ inline void wprep_one(const float* __restrict__ W,
                                 unsigned short* __restrict__ out, int tid) {
    const int lane = tid & 63;
    const int nt = (tid >> 6) % NT;
    const int ks = tid / (64 * NT);
    const int col = nt * 16 + (lane & 15);
    const int k0 = ks * 32 + (lane >> 4) * 8;
    half8 h8, l8;
#pragma unroll
    for (int e = 0; e < 8; ++e) {
        const float w = (col < F) ? W[(size_t)(k0 + e) * F + col] : 0.f;
        const _Float16 h = (_Float16)w;
        h8[e] = h;
        l8[e] = (_Float16)(w - (float)h);
    }
    half8* dst = (half8*)(out + (size_t)tid * 16);
    dst[0] = h8;
    dst[1] = l8;
}

__global__ __launch_bounds__(256) void k_prep(const float* __restrict__ W1,
                                              const float* __restrict__ W2,
                                              const float* __restrict__ W3,
                                              unsigned short* __restrict__ wf1,
                                              unsigned short* __restrict__ wf2,
                                              unsigned short* __restrict__ wf3,
                                              int* __restrict__ bcnt) {
    const int bid = blockIdx.x;
    if (bid == 8) {  // zero bucket counters
        for (int i = threadIdx.x; i < NB; i += 256) bcnt[i] = 0;
        return;
    }
    const int tid = bid * 256 + threadIdx.x;
    if (tid < 1024) wprep_one<128, 64, 4>(W1, wf1, tid);
    else if (tid < 1536) wprep_one<64, 64, 4>(W2, wf2, tid - 1024);
    else if (tid < 1920) wprep_one<64, 40, 3>(W3, wf3, tid - 1536);
}

// ---------------- phase A: block-aggregated bin by target range ----------------
// entry = (local_col << 17) | row   (requires n <= 131072)

__global__ __launch_bounds__(1024) void k_bin(const int* __restrict__ row,
                                              const int* __restrict__ col,
                                              int* __restrict__ bcnt,
                                              unsigned* __restrict__ bkt,
                                              int E, int npb) {
    __shared__ int hist[NB];
    __shared__ int fill[NB];
    const int tid = threadIdx.x;
    const int e0 = blockIdx.x * (1024 * BIN_ITER);
    if (tid < NB) hist[tid] = 0;
    __syncthreads();
    unsigned ent[BIN_ITER];
    int bb[BIN_ITER];
#pragma unroll
    for (int j = 0; j < BIN_ITER; ++j) {
        const int i = e0 + j * 1024 + tid;
        bb[j] = -1;
        ent[j] = 0;
        if (i < E) {
            const int c = col[i], r = row[i];
            const int b = c / npb;
            bb[j] = b;
            ent[j] = ((unsigned)(c - b * npb) << 17) | (unsigned)r;
            atomicAdd(&hist[b], 1);
        }
    }
    __syncthreads();
    if (tid < NB)
        fill[tid] = hist[tid] ? atomicAdd(&bcnt[tid], hist[tid]) : 0;
    __syncthreads();
#pragma unroll
    for (int j = 0; j < BIN_ITER; ++j) {
        if (bb[j] >= 0) {
            const int pos = atomicAdd(&fill[bb[j]], 1);
            if (pos < CAP)
                bkt[(size_t)bb[j] * CAP + pos] = ent[j];
        }
    }
}

// ---------------- bucket-base scan (single block, NB threads) ----------------

__global__ __launch_bounds__(NB) void k_bscan(const int* __restrict__ bcnt,
                                              int* __restrict__ bbase,
                                              int* __restrict__ rowptr, int E, int n) {
    __shared__ int s[NB];
    const int t = threadIdx.x;
    const int v = min(bcnt[t], CAP);
    s[t] = v;
    __syncthreads();
    for (int off = 1; off < NB; off <<= 1) {
        int u = (t >= off) ? s[t - off] : 0;
        __syncthreads();
        s[t] += u;
        __syncthreads();
    }
    bbase[t] = s[t] - v;  // exclusive
    if (t == 0) rowptr[n] = E;
}

// ---------------- phase B: per-bucket place + rowptr + dinv ----------------

__global__ __launch_bounds__(256) void k_place(const int* __restrict__ bcnt,
                                               const int* __restrict__ bbase,
                                               const unsigned* __restrict__ bkt,
                                               int* __restrict__ rowptr,
                                               float* __restrict__ dinv,
                                               int* __restrict__ srcidx,
                                               int n, int npb) {
    __shared__ int hist[128];      // npb <= 128
    __shared__ int pfx[128];
    __shared__ unsigned ent[CAP];
    const int b = blockIdx.x;
    const int tid = threadIdx.x;
    const int c0 = b * npb;
    const int nn = min(npb, n - c0);
    if (nn <= 0) return;
    const int bc = min(bcnt[b], CAP);
    const int base = bbase[b];
    for (int j = tid; j < nn; j += 256) hist[j] = 0;
    __syncthreads();
    for (int i = tid; i < bc; i += 256) {
        const unsigned e = bkt[(size_t)b * CAP + i];
        ent[i] = e;
        atomicAdd(&hist[e >> 17], 1);
    }
    __syncthreads();
    if (tid == 0) {
        int run = base;
        for (int j = 0; j < nn; ++j) { pfx[j] = run; run += hist[j]; }
    }
    __syncthreads();
    for (int j = tid; j < nn; j += 256) {
        rowptr[c0 + j] = pfx[j];
        dinv[c0 + j] = rsqrtf((float)(hist[j] + 1));  // +1 self loop
    }
    __syncthreads();
    for (int i = tid; i < bc; i += 256) {
        const unsigned e = ent[i];
        const int pos = atomicAdd(&pfx[e >> 17], 1);  // pfx reused as fill cursor
        srcidx[pos] = (int)(e & 0x1FFFFu);
    }
}

// ---------------- MFMA GEMM, f32 input (layer 1): split-f16 3-MFMA ----------------
// Y packed fp16 pairs (stride 32 half2), scaled by dinv[row]; rows >= n zeroed

template<int K, int NT>
__global__ __launch_bounds__(256) void gemm_f32in(const float* __restrict__ X,
                                                  const unsigned short* __restrict__ wfrag,
                                                  const float* __restrict__ dinv,
                                                  __half2* __restrict__ Y, int n) {
    const int lane = threadIdx.x & 63;
    const int wv = threadIdx.x >> 6;
    const int row0 = blockIdx.x * 64 + wv * 16;
    const int arow = row0 + (lane & 15);
    const bool aval = arow < n;

    f32x4 acc[NT];
#pragma unroll
    for (int t = 0; t < NT; ++t) acc[t] = (f32x4){0.f, 0.f, 0.f, 0.f};

#pragma unroll
    for (int ks = 0; ks < K / 32; ++ks) {
        float av[8];
        if (aval) {
            const float* ap = X + (size_t)arow * K + ks * 32 + (lane >> 4) * 8;
            const float4 p0 = *reinterpret_cast<const float4*>(ap);
            const float4 p1 = *reinterpret_cast<const float4*>(ap + 4);
            av[0] = p0.x; av[1] = p0.y; av[2] = p0.z; av[3] = p0.w;
            av[4] = p1.x; av[5] = p1.y; av[6] = p1.z; av[7] = p1.w;
        } else {
#pragma unroll
            for (int e = 0; e < 8; ++e) av[e] = 0.f;
        }
        half8 ah, al;
#pragma unroll
        for (int e = 0; e < 8; ++e) {
            const _Float16 h = (_Float16)av[e];
            ah[e] = h;
            al[e] = (_Float16)(av[e] - (float)h);
        }
#pragma unroll
        for (int t = 0; t < NT; ++t) {
            const half8* bp = (const half8*)(wfrag + (((size_t)ks * NT + t) * 64 + lane) * 16);
            const half8 bh = bp[0];
            const half8 bl = bp[1];
            acc[t] = __builtin_amdgcn_mfma_f32_16x16x32_f16(ah, bh, acc[t], 0, 0, 0);
            acc[t] = __builtin_amdgcn_mfma_f32_16x16x32_f16(al, bh, acc[t], 0, 0, 0);
            acc[t] = __builtin_amdgcn_mfma_f32_16x16x32_f16(ah, bl, acc[t], 0, 0, 0);
        }
    }

    const int col = lane & 15;
    const int rg = lane >> 4;
#pragma unroll
    for (int r = 0; r < 4; ++r) {
        const int orow = row0 + rg * 4 + r;          // < npad by grid construction
        const float di = (orow < n) ? dinv[orow] : 0.f;
#pragma unroll
        for (int t = 0; t < NT; ++t) {
            const float val = acc[t][r] * di;
            const float oth = __shfl_xor(val, 1);
            if (!(lane & 1))
                Y[(size_t)orow * (NT * 8) + t * 8 + (col >> 1)] = __floats2half2_rn(val, oth);
        }
    }
}

// ---------------- MFMA GEMM, fp16 input (layers 2,3): exact-A 2-MFMA ----------------
// MODE 0: Y packed fp16 * dinv (rows >= n zeroed) | MODE 1: Y f32 (stride 40) + bias

template<int K, int NT, int MODE>
__global__ __launch_bounds__(256) void gemm_f16in(const unsigned short* __restrict__ X,
                                                  const unsigned short* __restrict__ wfrag,
                                                  const float* __restrict__ dinv,
                                                  const float* __restrict__ bias,
                                                  void* __restrict__ Yv, int n) {
    const int lane = threadIdx.x & 63;
    const int wv = threadIdx.x >> 6;
    const int row0 = blockIdx.x * 64 + wv * 16;
    const int arow = row0 + (lane & 15);
    const bool aval = arow < n;

    f32x4 acc[NT];
#pragma unroll
    for (int t = 0; t < NT; ++t) acc[t] = (f32x4){0.f, 0.f, 0.f, 0.f};

#pragma unroll
    for (int ks = 0; ks < K / 32; ++ks) {
        half8 ah = {0, 0, 0, 0, 0, 0, 0, 0};
        if (aval)
            ah = *(const half8*)(X + (size_t)arow * K + ks * 32 + (lane >> 4) * 8);
#pragma unroll
        for (int t = 0; t < NT; ++t) {
            const half8* bp = (const half8*)(wfrag + (((size_t)ks * NT + t) * 64 + lane) * 16);
            const half8 bh = bp[0];
            const half8 bl = bp[1];
            acc[t] = __builtin_amdgcn_mfma_f32_16x16x32_f16(ah, bh, acc[t], 0, 0, 0);
            acc[t] = __builtin_amdgcn_mfma_f32_16x16x32_f16(ah, bl, acc[t], 0, 0, 0);
        }
    }

    const int col = lane & 15;
    const int rg = lane >> 4;
#pragma unroll
    for (int r = 0; r < 4; ++r) {
        const int orow = row0 + rg * 4 + r;
        if (MODE == 0) {
            const float di = (orow < n) ? dinv[orow] : 0.f;
            __half2* Y = (__half2*)Yv;
#pragma unroll
            for (int t = 0; t < NT; ++t) {
                const float val = acc[t][r] * di;
                const float oth = __shfl_xor(val, 1);
                if (!(lane & 1))
                    Y[(size_t)orow * (NT * 8) + t * 8 + (col >> 1)] = __floats2half2_rn(val, oth);
            }
        } else {
            float* Y = (float*)Yv;
#pragma unroll
            for (int t = 0; t < NT; ++t) {
                const int oc = t * 16 + col;
                if (orow < n && oc < 40)
                    Y[(size_t)orow * 40 + oc] = acc[t][r] + bias[oc];
            }
        }
    }
}

// ---------------- fp16 gather-reduce: persistent waves, LDS-staged offsets ----------------
// in: packed fp16 pairs, row stride 32 half2; row n (pad) must be all-zero.
// Fixed grid; each wave grid-strides over nodes. Lane p=l&31 owns feature pair
// (2p,2p+1); halves do even/odd edges. Inner loop: groups of 8 independent
// {ds_read(imm) -> v_add -> global_load -> v_pk_add_f16}. BN params hoisted.
// MODE 0: out = relu(bn(acc*dinv)) ; MODE 1: same * dinv ; MODE 2: acc*dinv

template<int MODE>
__global__ __launch_bounds__(256) void k_gather(const __half2* __restrict__ in,
                                                const int* __restrict__ rowptr,
                                                const int* __restrict__ srcidx,
                                                const float* __restrict__ dinv,
                                                const float* __restrict__ b,
                                                const float* __restrict__ g,
                                                const float* __restrict__ be,
                                                const float* __restrict__ m,
                                                const float* __restrict__ v,
                                                __half2* __restrict__ out,
                                                int n, int npad) {
    __shared__ unsigned offs[4][64];
    const int lane = threadIdx.x & 63;
    const int wslot = threadIdx.x >> 6;
    const int half = lane >> 5;
    const int p = lane & 31;
    const int wid0 = blockIdx.x * 4 + wslot;
    const int nwaves = gridDim.x * 4;
    const unsigned pconst = (unsigned)p * 4u;
    const char* inb = (const char*)in;

    // hoisted BN params (uniform across nodes)
    float sx = 0.f, sy = 0.f;
    float2 bb = {0.f, 0.f}, mm = {0.f, 0.f}, bee = {0.f, 0.f};
    if (MODE != 2) {
        bb = ((const float2*)b)[p];
        const float2 gg = ((const float2*)g)[p];
        bee = ((const float2*)be)[p];
        mm = ((const float2*)m)[p];
        const float2 vv = ((const float2*)v)[p];
        sx = gg.x * rsqrtf(vv.x + EPSV);
        sy = gg.y * rsqrtf(vv.y + EPSV);
    }

    for (int node = wid0; node < npad; node += nwaves) {
        if (node >= n) {  // pad node: keep pad rows of `out` zeroed
            if (!half) out[(size_t)node * 32 + p] = u2h(0u);
            continue;
        }
        const int s = rowptr[node], e = rowptr[node + 1];
        __half2 acc0 = u2h(0u), acc1 = u2h(0u), acc2 = u2h(0u), acc3 = u2h(0u);

        for (int base = s; base < e; base += 64) {
            const int c = min(64, e - base);
            unsigned idx = (unsigned)n;  // pad row (zeros) for out-of-range slots
            if (base + lane < e) idx = (unsigned)srcidx[base + lane];
            offs[wslot][lane] = idx * 128u;  // row byte offset
            for (int k8 = 0; k8 < 32; k8 += 8) {
                if (2 * k8 >= c) break;
                unsigned o[8], u[8];
#pragma unroll
                for (int j = 0; j < 8; ++j) o[j] = offs[wslot][2 * (k8 + j) + half];
#pragma unroll
                for (int j = 0; j < 8; ++j)
                    u[j] = *(const unsigned*)(inb + (size_t)(o[j] + pconst));
                acc0 = __hadd2(acc0, u2h(u[0])); acc1 = __hadd2(acc1, u2h(u[1]));
                acc2 = __hadd2(acc2, u2h(u[2])); acc3 = __hadd2(acc3, u2h(u[3]));
                acc0 = __hadd2(acc0, u2h(u[4])); acc1 = __hadd2(acc1, u2h(u[5]));
                acc2 = __hadd2(acc2, u2h(u[6])); acc3 = __hadd2(acc3, u2h(u[7]));
            }
        }
        __half2 acc = __hadd2(__hadd2(acc0, acc1), __hadd2(acc2, acc3));
        acc = __hadd2(acc, u2h(__shfl_xor(h2u(acc), 32)));
        // convert to f32, add self loop in f32
        float2 af = __half22float2(acc);
        const float2 sf = __half22float2(in[(size_t)node * 32 + p]);
        const float ax = af.x + sf.x, ay = af.y + sf.y;

        const float di = dinv[node];
        float ox, oy;
        if (MODE == 2) {
            ox = ax * di; oy = ay * di;
        } else {
            ox = fmaxf((ax * di + bb.x - mm.x) * sx + bee.x, 0.f);
            oy = fmaxf((ay * di + bb.y - mm.y) * sy + bee.y, 0.f);
            if (MODE == 1) { ox *= di; oy *= di; }
        }
        if (!half) out[(size_t)node * 32 + p] = __floats2half2_rn(ox, oy);
    }
}

// ---------------- launch ----------------

extern "C" void kernel_launch(void* const* d_in, const int* in_sizes, int n_in,
                              void* d_out, int out_size, void* d_ws, size_t ws_size,
                              hipStream_t stream) {
    const float* x   = (const float*)d_in[0];
    const int*   ei  = (const int*)d_in[1];
    const float* W1  = (const float*)d_in[2];
    const float* b1  = (const float*)d_in[3];
    const float* g1  = (const float*)d_in[4];
    const float* be1 = (const float*)d_in[5];
    const float* m1  = (const float*)d_in[6];
    const float* v1  = (const float*)d_in[7];
    const float* W2  = (const float*)d_in[8];
    const float* b2  = (const float*)d_in[9];
    const float* g2  = (const float*)d_in[10];
    const float* be2 = (const float*)d_in[11];
    const float* m2  = (const float*)d_in[12];
    const float* v2  = (const float*)d_in[13];
    const float* W3  = (const float*)d_in[14];
    const float* b3  = (const float*)d_in[15];

    const int n = in_sizes[0] / 128;
    const int E = in_sizes[1] / 2;
    const int* row  = ei;       // source nodes
    const int* colv = ei + E;   // target nodes
    const int npb = (n + NB - 1) / NB;    // nodes per bucket (98 for n=100k; <=128)
    const int gblk = (n >> 6) + 1;        // guarantees >=1 pad row (row n zeroed)
    const int npad = gblk * 64;

    char* base = (char*)d_ws;
    size_t off = 0;
    auto alloc = [&](size_t bytes) -> char* {
        char* p = base + off;
        off += (bytes + 255) & ~(size_t)255;
        return p;
    };
    int*      bcnt   = (int*)     alloc((size_t)NB * 4);
    int*      bbase  = (int*)     alloc((size_t)NB * 4);
    unsigned* bkt    = (unsigned*)alloc((size_t)NB * CAP * 4);
    int*      rowptr = (int*)     alloc((size_t)(n + 1) * 4);
    int*      srcidx = (int*)     alloc((size_t)E * 4);
    float*    dinv   = (float*)   alloc((size_t)n * 4);
    __half2*  hls1u  = (__half2*) alloc((size_t)npad * 32 * 4);   // (x@W1)*dinv   fp16
    __half2*  h1u    = (__half2*) alloc((size_t)npad * 32 * 4);   // h1            fp16
    __half2*  hls2u  = (__half2*) alloc((size_t)npad * 32 * 4);   // (h1@W2)*dinv  fp16
    __half2*  h2lsu  = (__half2*) alloc((size_t)npad * 32 * 4);   // h2*dinv       fp16
    __half2*  agg3u  = (__half2*) alloc((size_t)npad * 32 * 4);   // A_norm@h2     fp16
    unsigned short* wf1 = (unsigned short*)alloc((size_t)(128/32) * 4 * 64 * 32);
    unsigned short* wf2 = (unsigned short*)alloc((size_t)(64/32) * 4 * 64 * 32);
    unsigned short* wf3 = (unsigned short*)alloc((size_t)(64/32) * 3 * 64 * 32);
    float*    outp   = (float*)d_out;

    // prep: weight fragments + zero bucket counters (one kernel)
    k_prep<<<9, 256, 0, stream>>>(W1, W2, W3, wf1, wf2, wf3, bcnt);

    // CSR build (binned counting sort; also produces dinv)
    const int binblk = (E + 1024 * BIN_ITER - 1) / (1024 * BIN_ITER);
    k_bin<<<binblk, 1024, 0, stream>>>(row, colv, bcnt, bkt, E, npb);
    k_bscan<<<1, NB, 0, stream>>>(bcnt, bbase, rowptr, E, n);
    k_place<<<NB, 256, 0, stream>>>(bcnt, bbase, bkt, rowptr, dinv, srcidx, n, npb);

    const int ablk = 2048;  // persistent gather grid (8192 waves)
    // layer 1
    gemm_f32in<128, 4><<<gblk, 256, 0, stream>>>(x, wf1, dinv, hls1u, n);
    k_gather<0><<<ablk, 256, 0, stream>>>(hls1u, rowptr, srcidx, dinv,
                                          b1, g1, be1, m1, v1, h1u, n, npad);
    // layer 2
    gemm_f16in<64, 4, 0><<<gblk, 256, 0, stream>>>((const unsigned short*)h1u, wf2,
                                                   dinv, nullptr, hls2u, n);
    k_gather<1><<<ablk, 256, 0, stream>>>(hls2u, rowptr, srcidx, dinv,
                                          b2, g2, be2, m2, v2, h2lsu, n, npad);
    // layer 3: aggregate h2*dinv first, then transform 64->40
    k_gather<2><<<ablk, 256, 0, stream>>>(h2lsu, rowptr, srcidx, dinv,
                                          nullptr, nullptr, nullptr, nullptr, nullptr,
                                          agg3u, n, npad);
    gemm_f16in<64, 3, 1><<<gblk, 256, 0, stream>>>((const unsigned short*)agg3u, wf3,
                                                   dinv, b3, outp, n);
}

// Round 15
// 173.674 us; speedup vs baseline: 1.1350x; 1.0012x over previous
//
#include <hip/hip_runtime.h>
#include <hip/hip_fp16.h>

#define EPSV 1e-5f
#define NB  1024     // buckets for CSR binning (npb ~98, 7-bit local col fits 15-bit field)
#define CAP 2048     // bucket capacity (mean ~1563 at E=1.6M)
#define BIN_ITER 4   // edges per thread in k_bin (static register staging)

typedef short short8 __attribute__((ext_vector_type(8)));
typedef _Float16 half8 __attribute__((ext_vector_type(8)));
typedef float f32x4 __attribute__((ext_vector_type(4)));

__device__ inline unsigned h2u(__half2 h) { union { __half2 h; unsigned u; } c; c.h = h; return c.u; }
__device__ inline __half2 u2h(unsigned u) { union { unsigned u; __half2 h; } c; c.u = u; return c.h; }

// ---------------- W fragment prep + bcnt zeroing (one kernel) ----------------
// f16 split: w = wh + wl, wl = f16(w - wh) -> residual ~2^-22.
// frag (ks, nt, lane): elem e -> W[ks*32 + (lane>>4)*8 + e][nt*16 + (lane&15)]
// layout: out[tid*16] = 8 hi halves, then 8 lo halves

template<int K, int F, int NT>
__device__ inline void wprep_one(const float* __restrict__ W,
                                 unsigned short* __restrict__ out, int tid) {
    const int lane = tid & 63;
    const int nt = (tid >> 6) % NT;
    const int ks = tid / (64 * NT);
    const int col = nt * 16 + (lane & 15);
    const int k0 = ks * 32 + (lane >> 4) * 8;
    half8 h8, l8;
#pragma unroll
    for (int e = 0; e < 8; ++e) {
        const float w = (col < F) ? W[(size_t)(k0 + e) * F + col] : 0.f;
        const _Float16 h = (_Float16)w;
        h8[e] = h;
        l8[e] = (_Float16)(w - (float)h);
    }
    half8* dst = (half8*)(out + (size_t)tid * 16);
    dst[0] = h8;
    dst[1] = l8;
}

__global__ __launch_bounds__(256) void k_prep(const float* __restrict__ W1,
                                              const float* __restrict__ W2,
                                              const float* __restrict__ W3,
                                              unsigned short* __restrict__ wf1,
                                              unsigned short* __restrict__ wf2,
                                              unsigned short* __restrict__ wf3,
                                              int* __restrict__ bcnt) {
    const int bid = blockIdx.x;
    if (bid == 8) {  // zero bucket counters
        for (int i = threadIdx.x; i < NB; i += 256) bcnt[i] = 0;
        return;
    }
    const int tid = bid * 256 + threadIdx.x;
    if (tid < 1024) wprep_one<128, 64, 4>(W1, wf1, tid);
    else if (tid < 1536) wprep_one<64, 64, 4>(W2, wf2, tid - 1024);
    else if (tid < 1920) wprep_one<64, 40, 3>(W3, wf3, tid - 1536);
}

// ---------------- phase A: block-aggregated bin by target range ----------------
// entry = (local_col << 17) | row   (requires n <= 131072)

__global__ __launch_bounds__(1024) void k_bin(const int* __restrict__ row,
                                              const int* __restrict__ col,
                                              int* __restrict__ bcnt,
                                              unsigned* __restrict__ bkt,
                                              int E, int npb) {
    __shared__ int hist[NB];
    __shared__ int fill[NB];
    const int tid = threadIdx.x;
    const int e0 = blockIdx.x * (1024 * BIN_ITER);
    if (tid < NB) hist[tid] = 0;
    __syncthreads();
    unsigned ent[BIN_ITER];
    int bb[BIN_ITER];
#pragma unroll
    for (int j = 0; j < BIN_ITER; ++j) {
        const int i = e0 + j * 1024 + tid;
        bb[j] = -1;
        ent[j] = 0;
        if (i < E) {
            const int c = col[i], r = row[i];
            const int b = c / npb;
            bb[j] = b;
            ent[j] = ((unsigned)(c - b * npb) << 17) | (unsigned)r;
            atomicAdd(&hist[b], 1);
        }
    }
    __syncthreads();
    if (tid < NB)
        fill[tid] = hist[tid] ? atomicAdd(&bcnt[tid], hist[tid]) : 0;
    __syncthreads();
#pragma unroll
    for (int j = 0; j < BIN_ITER; ++j) {
        if (bb[j] >= 0) {
            const int pos = atomicAdd(&fill[bb[j]], 1);
            if (pos < CAP)
                bkt[(size_t)bb[j] * CAP + pos] = ent[j];
        }
    }
}

// ---------------- bucket-base scan (single block, NB threads) ----------------

__global__ __launch_bounds__(NB) void k_bscan(const int* __restrict__ bcnt,
                                              int* __restrict__ bbase,
                                              int* __restrict__ rowptr, int E, int n) {
    __shared__ int s[NB];
    const int t = threadIdx.x;
    const int v = min(bcnt[t], CAP);
    s[t] = v;
    __syncthreads();
    for (int off = 1; off < NB; off <<= 1) {
        int u = (t >= off) ? s[t - off] : 0;
        __syncthreads();
        s[t] += u;
        __syncthreads();
    }
    bbase[t] = s[t] - v;  // exclusive
    if (t == 0) rowptr[n] = E;
}

// ---------------- phase B: per-bucket place + rowptr + dinv ----------------

__global__ __launch_bounds__(256) void k_place(const int* __restrict__ bcnt,
                                               const int* __restrict__ bbase,
                                               const unsigned* __restrict__ bkt,
                                               int* __restrict__ rowptr,
                                               float* __restrict__ dinv,
                                               int* __restrict__ srcidx,
                                               int n, int npb) {
    __shared__ int hist[128];      // npb <= 128
    __shared__ int pfx[128];
    __shared__ unsigned ent[CAP];
    const int b = blockIdx.x;
    const int tid = threadIdx.x;
    const int c0 = b * npb;
    const int nn = min(npb, n - c0);
    if (nn <= 0) return;
    const int bc = min(bcnt[b], CAP);
    const int base = bbase[b];
    for (int j = tid; j < nn; j += 256) hist[j] = 0;
    __syncthreads();
    for (int i = tid; i < bc; i += 256) {
        const unsigned e = bkt[(size_t)b * CAP + i];
        ent[i] = e;
        atomicAdd(&hist[e >> 17], 1);
    }
    __syncthreads();
    if (tid == 0) {
        int run = base;
        for (int j = 0; j < nn; ++j) { pfx[j] = run; run += hist[j]; }
    }
    __syncthreads();
    for (int j = tid; j < nn; j += 256) {
        rowptr[c0 + j] = pfx[j];
        dinv[c0 + j] = rsqrtf((float)(hist[j] + 1));  // +1 self loop
    }
    __syncthreads();
    for (int i = tid; i < bc; i += 256) {
        const unsigned e = ent[i];
        const int pos = atomicAdd(&pfx[e >> 17], 1);  // pfx reused as fill cursor
        srcidx[pos] = (int)(e & 0x1FFFFu);
    }
}

// ---------------- MFMA GEMM, f32 input (layer 1): split-f16 3-MFMA ----------------
// Y packed fp16 pairs (stride 32 half2), scaled by dinv[row]; rows >= n zeroed

template<int K, int NT>
__global__ __launch_bounds__(256) void gemm_f32in(const float* __restrict__ X,
                                                  const unsigned short* __restrict__ wfrag,
                                                  const float* __restrict__ dinv,
                                                  __half2* __restrict__ Y, int n) {
    const int lane = threadIdx.x & 63;
    const int wv = threadIdx.x >> 6;
    const int row0 = blockIdx.x * 64 + wv * 16;
    const int arow = row0 + (lane & 15);
    const bool aval = arow < n;

    f32x4 acc[NT];
#pragma unroll
    for (int t = 0; t < NT; ++t) acc[t] = (f32x4){0.f, 0.f, 0.f, 0.f};

#pragma unroll
    for (int ks = 0; ks < K / 32; ++ks) {
        float av[8];
        if (aval) {
            const float* ap = X + (size_t)arow * K + ks * 32 + (lane >> 4) * 8;
            const float4 p0 = *reinterpret_cast<const float4*>(ap);
            const float4 p1 = *reinterpret_cast<const float4*>(ap + 4);
            av[0] = p0.x; av[1] = p0.y; av[2] = p0.z; av[3] = p0.w;
            av[4] = p1.x; av[5] = p1.y; av[6] = p1.z; av[7] = p1.w;
        } else {
#pragma unroll
            for (int e = 0; e < 8; ++e) av[e] = 0.f;
        }
        half8 ah, al;
#pragma unroll
        for (int e = 0; e < 8; ++e) {
            const _Float16 h = (_Float16)av[e];
            ah[e] = h;
            al[e] = (_Float16)(av[e] - (float)h);
        }
#pragma unroll
        for (int t = 0; t < NT; ++t) {
            const half8* bp = (const half8*)(wfrag + (((size_t)ks * NT + t) * 64 + lane) * 16);
            const half8 bh = bp[0];
            const half8 bl = bp[1];
            acc[t] = __builtin_amdgcn_mfma_f32_16x16x32_f16(ah, bh, acc[t], 0, 0, 0);
            acc[t] = __builtin_amdgcn_mfma_f32_16x16x32_f16(al, bh, acc[t], 0, 0, 0);
            acc[t] = __builtin_amdgcn_mfma_f32_16x16x32_f16(ah, bl, acc[t], 0, 0, 0);
        }
    }

    const int col = lane & 15;
    const int rg = lane >> 4;
#pragma unroll
    for (int r = 0; r < 4; ++r) {
        const int orow = row0 + rg * 4 + r;          // < npad by grid construction
        const float di = (orow < n) ? dinv[orow] : 0.f;
#pragma unroll
        for (int t = 0; t < NT; ++t) {
            const float val = acc[t][r] * di;
            const float oth = __shfl_xor(val, 1);
            if (!(lane & 1))
                Y[(size_t)orow * (NT * 8) + t * 8 + (col >> 1)] = __floats2half2_rn(val, oth);
        }
    }
}

// ---------------- MFMA GEMM, fp16 input (layers 2,3): exact-A 2-MFMA ----------------
// MODE 0: Y packed fp16 * dinv (rows >= n zeroed) | MODE 1: Y f32 (stride 40) + bias

template<int K, int NT, int MODE>
__global__ __launch_bounds__(256) void gemm_f16in(const unsigned short* __restrict__ X,
                                                  const unsigned short* __restrict__ wfrag,
                                                  const float* __restrict__ dinv,
                                                  const float* __restrict__ bias,
                                                  void* __restrict__ Yv, int n) {
    const int lane = threadIdx.x & 63;
    const int wv = threadIdx.x >> 6;
    const int row0 = blockIdx.x * 64 + wv * 16;
    const int arow = row0 + (lane & 15);
    const bool aval = arow < n;

    f32x4 acc[NT];
#pragma unroll
    for (int t = 0; t < NT; ++t) acc[t] = (f32x4){0.f, 0.f, 0.f, 0.f};

#pragma unroll
    for (int ks = 0; ks < K / 32; ++ks) {
        half8 ah = {0, 0, 0, 0, 0, 0, 0, 0};
        if (aval)
            ah = *(const half8*)(X + (size_t)arow * K + ks * 32 + (lane >> 4) * 8);
#pragma unroll
        for (int t = 0; t < NT; ++t) {
            const half8* bp = (const half8*)(wfrag + (((size_t)ks * NT + t) * 64 + lane) * 16);
            const half8 bh = bp[0];
            const half8 bl = bp[1];
            acc[t] = __builtin_amdgcn_mfma_f32_16x16x32_f16(ah, bh, acc[t], 0, 0, 0);
            acc[t] = __builtin_amdgcn_mfma_f32_16x16x32_f16(ah, bl, acc[t], 0, 0, 0);
        }
    }

    const int col = lane & 15;
    const int rg = lane >> 4;
#pragma unroll
    for (int r = 0; r < 4; ++r) {
        const int orow = row0 + rg * 4 + r;
        if (MODE == 0) {
            const float di = (orow < n) ? dinv[orow] : 0.f;
            __half2* Y = (__half2*)Yv;
#pragma unroll
            for (int t = 0; t < NT; ++t) {
                const float val = acc[t][r] * di;
                const float oth = __shfl_xor(val, 1);
                if (!(lane & 1))
                    Y[(size_t)orow * (NT * 8) + t * 8 + (col >> 1)] = __floats2half2_rn(val, oth);
            }
        } else {
            float* Y = (float*)Yv;
#pragma unroll
            for (int t = 0; t < NT; ++t) {
                const int oc = t * 16 + col;
                if (orow < n && oc < 40)
                    Y[(size_t)orow * 40 + oc] = acc[t][r] + bias[oc];
            }
        }
    }
}

// ---------------- fp16 gather-reduce: persistent waves, LDS-staged offsets ----------------
// in: packed fp16 pairs, row stride 32 half2; row n (pad) must be all-zero.
// Fixed grid; each wave grid-strides over nodes. Lane p=l&31 owns feature pair
// (2p,2p+1); halves do even/odd edges. Inner loop: groups of 8 independent
// {ds_read(imm) -> v_add -> global_load -> v_pk_add_f16}. BN params hoisted.
// MODE 0: out = relu(bn(acc*dinv)) ; MODE 1: same * dinv ; MODE 2: acc*dinv

template<int MODE>
__global__ __launch_bounds__(256) void k_gather(const __half2* __restrict__ in,
                                                const int* __restrict__ rowptr,
                                                const int* __restrict__ srcidx,
                                                const float* __restrict__ dinv,
                                                const float* __restrict__ b,
                                                const float* __restrict__ g,
                                                const float* __restrict__ be,
                                                const float* __restrict__ m,
                                                const float* __restrict__ v,
                                                __half2* __restrict__ out,
                                                int n, int npad) {
    __shared__ unsigned offs[4][64];
    const int lane = threadIdx.x & 63;
    const int wslot = threadIdx.x >> 6;
    const int half = lane >> 5;
    const int p = lane & 31;
    const int wid0 = blockIdx.x * 4 + wslot;
    const int nwaves = gridDim.x * 4;
    const unsigned pconst = (unsigned)p * 4u;
    const char* inb = (const char*)in;

    // hoisted BN params (uniform across nodes)
    float sx = 0.f, sy = 0.f;
    float2 bb = {0.f, 0.f}, mm = {0.f, 0.f}, bee = {0.f, 0.f};
    if (MODE != 2) {
        bb = ((const float2*)b)[p];
        const float2 gg = ((const float2*)g)[p];
        bee = ((const float2*)be)[p];
        mm = ((const float2*)m)[p];
        const float2 vv = ((const float2*)v)[p];
        sx = gg.x * rsqrtf(vv.x + EPSV);
        sy = gg.y * rsqrtf(vv.y + EPSV);
    }

    for (int node = wid0; node < npad; node += nwaves) {
        if (node >= n) {  // pad node: keep pad rows of `out` zeroed
            if (!half) out[(size_t)node * 32 + p] = u2h(0u);
            continue;
        }
        const int s = rowptr[node], e = rowptr[node + 1];
        __half2 acc0 = u2h(0u), acc1 = u2h(0u), acc2 = u2h(0u), acc3 = u2h(0u);

        for (int base = s; base < e; base += 64) {
            const int c = min(64, e - base);
            unsigned idx = (unsigned)n;  // pad row (zeros) for out-of-range slots
            if (base + lane < e) idx = (unsigned)srcidx[base + lane];
            offs[wslot][lane] = idx * 128u;  // row byte offset
            for (int k8 = 0; k8 < 32; k8 += 8) {
                if (2 * k8 >= c) break;
                unsigned o[8], u[8];
#pragma unroll
                for (int j = 0; j < 8; ++j) o[j] = offs[wslot][2 * (k8 + j) + half];
#pragma unroll
                for (int j = 0; j < 8; ++j)
                    u[j] = *(const unsigned*)(inb + (size_t)(o[j] + pconst));
                acc0 = __hadd2(acc0, u2h(u[0])); acc1 = __hadd2(acc1, u2h(u[1]));
                acc2 = __hadd2(acc2, u2h(u[2])); acc3 = __hadd2(acc3, u2h(u[3]));
                acc0 = __hadd2(acc0, u2h(u[4])); acc1 = __hadd2(acc1, u2h(u[5]));
                acc2 = __hadd2(acc2, u2h(u[6])); acc3 = __hadd2(acc3, u2h(u[7]));
            }
        }
        __half2 acc = __hadd2(__hadd2(acc0, acc1), __hadd2(acc2, acc3));
        acc = __hadd2(acc, u2h(__shfl_xor(h2u(acc), 32)));
        // convert to f32, add self loop in f32
        float2 af = __half22float2(acc);
        const float2 sf = __half22float2(in[(size_t)node * 32 + p]);
        const float ax = af.x + sf.x, ay = af.y + sf.y;

        const float di = dinv[node];
        float ox, oy;
        if (MODE == 2) {
            ox = ax * di; oy = ay * di;
        } else {
            ox = fmaxf((ax * di + bb.x - mm.x) * sx + bee.x, 0.f);
            oy = fmaxf((ay * di + bb.y - mm.y) * sy + bee.y, 0.f);
            if (MODE == 1) { ox *= di; oy *= di; }
        }
        if (!half) out[(size_t)node * 32 + p] = __floats2half2_rn(ox, oy);
    }
}

// ---------------- launch ----------------

extern "C" void kernel_launch(void* const* d_in, const int* in_sizes, int n_in,
                              void* d_out, int out_size, void* d_ws, size_t ws_size,
                              hipStream_t stream) {
    const float* x   = (const float*)d_in[0];
    const int*   ei  = (const int*)d_in[1];
    const float* W1  = (const float*)d_in[2];
    const float* b1  = (const float*)d_in[3];
    const float* g1  = (const float*)d_in[4];
    const float* be1 = (const float*)d_in[5];
    const float* m1  = (const float*)d_in[6];
    const float* v1  = (const float*)d_in[7];
    const float* W2  = (const float*)d_in[8];
    const float* b2  = (const float*)d_in[9];
    const float* g2  = (const float*)d_in[10];
    const float* be2 = (const float*)d_in[11];
    const float* m2  = (const float*)d_in[12];
    const float* v2  = (const float*)d_in[13];
    const float* W3  = (const float*)d_in[14];
    const float* b3  = (const float*)d_in[15];

    const int n = in_sizes[0] / 128;
    const int E = in_sizes[1] / 2;
    const int* row  = ei;       // source nodes
    const int* colv = ei + E;   // target nodes
    const int npb = (n + NB - 1) / NB;    // nodes per bucket (98 for n=100k; <=128)
    const int gblk = (n >> 6) + 1;        // guarantees >=1 pad row (row n zeroed)
    const int npad = gblk * 64;

    char* base = (char*)d_ws;
    size_t off = 0;
    auto alloc = [&](size_t bytes) -> char* {
        char* p = base + off;
        off += (bytes + 255) & ~(size_t)255;
        return p;
    };
    int*      bcnt   = (int*)     alloc((size_t)NB * 4);
    int*      bbase  = (int*)     alloc((size_t)NB * 4);
    unsigned* bkt    = (unsigned*)alloc((size_t)NB * CAP * 4);
    int*      rowptr = (int*)     alloc((size_t)(n + 1) * 4);
    int*      srcidx = (int*)     alloc((size_t)E * 4);
    float*    dinv   = (float*)   alloc((size_t)n * 4);
    __half2*  hls1u  = (__half2*) alloc((size_t)npad * 32 * 4);   // (x@W1)*dinv   fp16
    __half2*  h1u    = (__half2*) alloc((size_t)npad * 32 * 4);   // h1            fp16
    __half2*  hls2u  = (__half2*) alloc((size_t)npad * 32 * 4);   // (h1@W2)*dinv  fp16
    __half2*  h2lsu  = (__half2*) alloc((size_t)npad * 32 * 4);   // h2*dinv       fp16
    __half2*  agg3u  = (__half2*) alloc((size_t)npad * 32 * 4);   // A_norm@h2     fp16
    unsigned short* wf1 = (unsigned short*)alloc((size_t)(128/32) * 4 * 64 * 32);
    unsigned short* wf2 = (unsigned short*)alloc((size_t)(64/32) * 4 * 64 * 32);
    unsigned short* wf3 = (unsigned short*)alloc((size_t)(64/32) * 3 * 64 * 32);
    float*    outp   = (float*)d_out;

    // prep: weight fragments + zero bucket counters (one kernel)
    k_prep<<<9, 256, 0, stream>>>(W1, W2, W3, wf1, wf2, wf3, bcnt);

    // CSR build (binned counting sort; also produces dinv)
    const int binblk = (E + 1024 * BIN_ITER - 1) / (1024 * BIN_ITER);
    k_bin<<<binblk, 1024, 0, stream>>>(row, colv, bcnt, bkt, E, npb);
    k_bscan<<<1, NB, 0, stream>>>(bcnt, bbase, rowptr, E, n);
    k_place<<<NB, 256, 0, stream>>>(bcnt, bbase, bkt, rowptr, dinv, srcidx, n, npb);

    const int ablk = 2048;  // persistent gather grid (8192 waves)
    // layer 1
    gemm_f32in<128, 4><<<gblk, 256, 0, stream>>>(x, wf1, dinv, hls1u, n);
    k_gather<0><<<ablk, 256, 0, stream>>>(hls1u, rowptr, srcidx, dinv,
                                          b1, g1, be1, m1, v1, h1u, n, npad);
    // layer 2
    gemm_f16in<64, 4, 0><<<gblk, 256, 0, stream>>>((const unsigned short*)h1u, wf2,
                                                   dinv, nullptr, hls2u, n);
    k_gather<1><<<ablk, 256, 0, stream>>>(hls2u, rowptr, srcidx, dinv,
                                          b2, g2, be2, m2, v2, h2lsu, n, npad);
    // layer 3: aggregate h2*dinv first, then transform 64->40
    k_gather<2><<<ablk, 256, 0, stream>>>(h2lsu, rowptr, srcidx, dinv,
                                          nullptr, nullptr, nullptr, nullptr, nullptr,
                                          agg3u, n, npad);
    gemm_f16in<64, 3, 1><<<gblk, 256, 0, stream>>>((const unsigned short*)agg3u, wf3,
                                                   dinv, b3, outp, n);
}